// Round 10
// baseline (1042.208 us; speedup 1.0000x reference)
//
#include <hip/hip_runtime.h>

// Problem constants (from reference)
#define NU 200000
#define NI 100000
#define DIM 64
#define NE 3200000
#define NT (NU + NI)                     // concatenated destination count
#define CHUNK 2048                       // elements per scan block (256 thr x 8)
#define NB ((NT + CHUNK - 1) / CHUNK)    // 147 scan blocks

static_assert(NB <= 256, "scan prefix assumes block sums fit one 256-thread block");
static_assert((NE & 3) == 0, "int4 edge vectorization assumes NE % 4 == 0");

// Established (R0-R8):
//  - ALL float inputs f32; edges int32, dict order. Output F32, users then items.
//  - Edge-order detector (flag[3]) validated in R7.
// SCATTER IS CLOSED (R11-R15 A/B): two 4 B dword stores/slot into two arrays,
//  1 edge/thread, 3200x256 grid-stride -> ~370-400 us. All variants slower:
//  {2x dword eid: 590} {1x dwordx2: 580} {2x dwordx2: 575}. DO NOT TOUCH.
// SPMM experiments: 4-group float4 restructure -90 us (R12); 2x unroll null
//  (R14); NT hints null (R17). => saturated at 4-8 gathers in flight/wave;
//  L2-miss-fill request-rate limit on random 256 B fills. ~555 us for 1.64 GB.
// R15: eid-indirection costs +215 us (dependent random reads don't hide).
// R18 (consolidation): (a) fuse the two spmm launches into ONE kernel
//  (rowptr index == w for both sides; kills launch gap + tail bubble, and
//  finally surfaces spmm counters in the top-5); (b) hipMemsetAsync replaces
//  zero kernel (flag+cnt contiguous; capture-safe); (c) scan2 folded into
//  scan3 (per-block self-prefix of the 147 block sums in LDS).

typedef float nfloat4 __attribute__((ext_vector_type(4)));

__device__ __forceinline__ int iclamp(int x, int lo, int hi) {
    return x < lo ? lo : (x > hi ? hi : x);
}

__global__ void zero_f32_kernel(float* __restrict__ p, long long n) {
    long long i = (long long)blockIdx.x * blockDim.x + threadIdx.x;
    long long stride = (long long)gridDim.x * blockDim.x;
    for (; i < n; i += stride) p[i] = 0.0f;
}

// flag: [3]=edge_swap  [10]=maxA [11]=maxB  (validated in R7)
__global__ void edge_detect_kernel(const int* __restrict__ a, const int* __restrict__ b,
                                   int n, int* __restrict__ flag) {
    int i = blockIdx.x * blockDim.x + threadIdx.x;
    int stride = gridDim.x * blockDim.x;
    int ma = 0, mb = 0;
    for (; i < n; i += stride) {
        ma = max(ma, a[i]);
        mb = max(mb, b[i]);
    }
    #pragma unroll
    for (int d = 32; d > 0; d >>= 1) {
        ma = max(ma, __shfl_down(ma, d, 64));
        mb = max(mb, __shfl_down(mb, d, 64));
    }
    if ((threadIdx.x & 63) == 0) {
        atomicMax(&flag[10], ma);
        atomicMax(&flag[11], mb);
    }
}
__global__ void finalize_kernel(int* __restrict__ flag) {
    if (threadIdx.x == 0 && blockIdx.x == 0) {
        int ma = flag[10], mb = flag[11];
        flag[3] = (mb >= NI && ma < NI) ? 1 : 0;
    }
}

// ---------------------------------------------------------------------------
// CSR build: histogram over concatenated destinations (users [0,NU), items
// [NU,NT)). int4-vectorized edge reads; int atomics are cheap packets.
// ---------------------------------------------------------------------------
__global__ __launch_bounds__(256) void hist_kernel(
        const int* __restrict__ a, const int* __restrict__ b,
        const int* __restrict__ flag, int* __restrict__ cnt) {
    int sw = flag[3];
    const int4* eu4 = (const int4*)(sw ? b : a);
    const int4* ei4 = (const int4*)(sw ? a : b);
    int e4 = blockIdx.x * blockDim.x + threadIdx.x;
    int stride = gridDim.x * blockDim.x;
    for (; e4 < NE / 4; e4 += stride) {
        int4 uu = eu4[e4];
        int4 ii = ei4[e4];
        atomicAdd(&cnt[iclamp(uu.x, 0, NU - 1)], 1);
        atomicAdd(&cnt[iclamp(uu.y, 0, NU - 1)], 1);
        atomicAdd(&cnt[iclamp(uu.z, 0, NU - 1)], 1);
        atomicAdd(&cnt[iclamp(uu.w, 0, NU - 1)], 1);
        atomicAdd(&cnt[NU + iclamp(ii.x, 0, NI - 1)], 1);
        atomicAdd(&cnt[NU + iclamp(ii.y, 0, NI - 1)], 1);
        atomicAdd(&cnt[NU + iclamp(ii.z, 0, NI - 1)], 1);
        atomicAdd(&cnt[NU + iclamp(ii.w, 0, NI - 1)], 1);
    }
}

// Per-block sums of cnt (CHUNK=2048 elements per block) -> bsum[NB] (raw).
__global__ __launch_bounds__(256) void scan1_kernel(const int* __restrict__ cnt,
                                                    int* __restrict__ bsum) {
    int b = blockIdx.x, t = threadIdx.x;
    int base = b * CHUNK;
    int sum = 0;
    #pragma unroll
    for (int k = 0; k < 8; ++k) {
        int idx = base + k * 256 + t;
        if (idx < NT) sum += cnt[idx];
    }
    #pragma unroll
    for (int d = 32; d > 0; d >>= 1) sum += __shfl_down(sum, d, 64);
    __shared__ int wsum[4];
    if ((t & 63) == 0) wsum[t >> 6] = sum;
    __syncthreads();
    if (t == 0) bsum[b] = wsum[0] + wsum[1] + wsum[2] + wsum[3];
}

// scan3 with the former scan2 folded in: each block scans the RAW bsum[NB]
// in LDS to get its own exclusive block prefix (147 ints — trivial), then
// writes rowptr/cursor for its 2048 cnt elements. One fewer launch.
__global__ __launch_bounds__(256) void scan3_kernel(const int* __restrict__ cnt,
                                                    const int* __restrict__ bsum,
                                                    int* __restrict__ rowptr,
                                                    int* __restrict__ cursor) {
    int b = blockIdx.x, t = threadIdx.x;
    // --- block-prefix from raw bsum (inclusive scan in LDS) ---
    __shared__ int pre[256];
    pre[t] = (t < NB) ? bsum[t] : 0;
    __syncthreads();
    for (int off = 1; off < 256; off <<= 1) {
        int v = (t >= off) ? pre[t - off] : 0;
        __syncthreads();
        pre[t] += v;
        __syncthreads();
    }
    int bpre = (b == 0) ? 0 : pre[b - 1];   // exclusive prefix for this block
    // --- local scan of this block's 2048 elements (8/thread contiguous) ---
    int base = b * CHUNK + t * 8;
    int v[8];
    int s = 0;
    #pragma unroll
    for (int k = 0; k < 8; ++k) {
        int idx = base + k;
        v[k] = (idx < NT) ? cnt[idx] : 0;
        s += v[k];
    }
    __shared__ int sh[256];
    sh[t] = s;
    __syncthreads();
    for (int off = 1; off < 256; off <<= 1) {
        int x = (t >= off) ? sh[t - off] : 0;
        __syncthreads();
        sh[t] += x;
        __syncthreads();
    }
    int run = (t == 0 ? 0 : sh[t - 1]) + bpre;
    #pragma unroll
    for (int k = 0; k < 8; ++k) {
        int idx = base + k;
        if (idx < NT) {
            rowptr[idx] = run;
            cursor[idx] = run;
            run += v[k];
        }
        if (idx == NT - 1) rowptr[NT] = run;   // == 2*NE
    }
}

// Scatter edges into sorted slots — EXACT R11/R14 form (proven ~370-400 us).
// Two scattered 4 B dword stores per slot into two separate arrays. Every
// measured variation is slower (see header). DO NOT TOUCH.
__global__ __launch_bounds__(256) void scatter_kernel(
        const int* __restrict__ a, const int* __restrict__ b,
        const int* __restrict__ flag, const float* __restrict__ ev,
        int* __restrict__ cursor, int* __restrict__ colS, float* __restrict__ valS) {
    int sw = flag[3];
    const int* eu = sw ? b : a;
    const int* ei = sw ? a : b;
    int e = blockIdx.x * blockDim.x + threadIdx.x;
    int stride = gridDim.x * blockDim.x;
    for (; e < NE; e += stride) {
        int u = iclamp(eu[e], 0, NU - 1);
        int i = iclamp(ei[e], 0, NI - 1);
        float v = ev[e];
        int p0 = atomicAdd(&cursor[u], 1);       // user slot: stores item idx
        colS[p0] = i; valS[p0] = v;
        int p1 = atomicAdd(&cursor[NU + i], 1);  // item slot: stores user idx
        colS[p1] = u; valS[p1] = v;
    }
}

// ---------------------------------------------------------------------------
// Fused gather SpMM: ONE kernel for both sides. Wave w < NU: user row
// (gathers item_emb); else item row (gathers user_emb). rowptr index is w in
// both cases. Inner loop byte-identical to R17's proven body: 16-lane groups,
// float4 slices, 2x unroll (8 gathers in flight), NT stream loads/stores.
// Degree-0 rows write 0 (covers the 0xAA-poisoned output, no zero pass).
// ---------------------------------------------------------------------------
__global__ __launch_bounds__(256) void spmm_fused_kernel(
        const int* __restrict__ rowptr, const int* __restrict__ colS,
        const float* __restrict__ valS,
        const float* __restrict__ item_emb, const float* __restrict__ user_emb,
        float* __restrict__ out_users, float* __restrict__ out_items) {
    int w = (int)(((long long)blockIdx.x * blockDim.x + threadIdx.x) >> 6);
    int lane = threadIdx.x & 63;
    if (w >= NT) return;
    const float* emb  = (w < NU) ? item_emb : user_emb;
    float*       optr = (w < NU) ? (out_users + (size_t)w * DIM)
                                 : (out_items + (size_t)(w - NU) * DIM);
    int g = lane >> 4;          // edge group 0..3
    int q = lane & 15;          // float4 slice within row
    int s = rowptr[w];
    int e = rowptr[w + 1];
    float ax0 = 0.f, ay0 = 0.f, az0 = 0.f, aw0 = 0.f;
    float ax1 = 0.f, ay1 = 0.f, az1 = 0.f, aw1 = 0.f;
    int k = s + g;
    for (; k + 4 < e; k += 8) {              // both k and k+4 valid
        int   c0 = __builtin_nontemporal_load(&colS[k]);
        float v0 = __builtin_nontemporal_load(&valS[k]);
        int   c1 = __builtin_nontemporal_load(&colS[k + 4]);
        float v1 = __builtin_nontemporal_load(&valS[k + 4]);
        nfloat4 x0 = ((const nfloat4*)(emb + (size_t)c0 * DIM))[q];
        nfloat4 x1 = ((const nfloat4*)(emb + (size_t)c1 * DIM))[q];
        ax0 += v0 * x0.x; ay0 += v0 * x0.y; az0 += v0 * x0.z; aw0 += v0 * x0.w;
        ax1 += v1 * x1.x; ay1 += v1 * x1.y; az1 += v1 * x1.z; aw1 += v1 * x1.w;
    }
    if (k < e) {                             // at most one leftover per group
        int   c = __builtin_nontemporal_load(&colS[k]);
        float v = __builtin_nontemporal_load(&valS[k]);
        nfloat4 x = ((const nfloat4*)(emb + (size_t)c * DIM))[q];
        ax0 += v * x.x; ay0 += v * x.y; az0 += v * x.z; aw0 += v * x.w;
    }
    float ax = ax0 + ax1, ay = ay0 + ay1, az = az0 + az1, aw = aw0 + aw1;
    // reduce the 4 edge-groups (lanes l, l^16, l^32, l^48 share slice q)
    ax += __shfl_xor(ax, 16, 64); ay += __shfl_xor(ay, 16, 64);
    az += __shfl_xor(az, 16, 64); aw += __shfl_xor(aw, 16, 64);
    ax += __shfl_xor(ax, 32, 64); ay += __shfl_xor(ay, 32, 64);
    az += __shfl_xor(az, 32, 64); aw += __shfl_xor(aw, 32, 64);
    if (g == 0) {
        nfloat4 r; r.x = ax; r.y = ay; r.z = az; r.w = aw;
        __builtin_nontemporal_store(r, &((nfloat4*)optr)[q]);
    }
}

// ---------------------------------------------------------------------------
// Fallback (R8 path): direct fp-atomic accumulate — used only if ws too small.
// ---------------------------------------------------------------------------
__global__ __launch_bounds__(256) void edge_atomic_kernel(
        const int* __restrict__ a, const int* __restrict__ b,
        const int* __restrict__ flag,
        const float* __restrict__ ev,
        const float* __restrict__ uemb, const float* __restrict__ iemb,
        float* __restrict__ outU, float* __restrict__ outI) {
    int sw = flag[3];
    const int* eu = sw ? b : a;
    const int* ei = sw ? a : b;
    long long t = (long long)blockIdx.x * blockDim.x + threadIdx.x;
    int lane = (int)(t & 63);
    long long e = t >> 6;
    if (e >= NE) return;
    int u = iclamp(eu[e], 0, NU - 1);
    int i = iclamp(ei[e], 0, NI - 1);
    float v  = ev[e];
    float xu = uemb[(size_t)u * DIM + lane];
    float xi = iemb[(size_t)i * DIM + lane];
    atomicAdd(&outU[(size_t)u * DIM + lane], v * xi);
    atomicAdd(&outI[(size_t)i * DIM + lane], v * xu);
}

// ===========================================================================
extern "C" void kernel_launch(void* const* d_in, const int* in_sizes, int n_in,
                              void* d_out, int out_size, void* d_ws, size_t ws_size,
                              hipStream_t stream) {
    // Identify embedding slots by element count (insurance against slot swap).
    const float* user_emb = (const float*)d_in[0];
    const float* item_emb = (const float*)d_in[1];
    if (in_sizes[0] == NI * DIM && in_sizes[1] == NU * DIM) {
        user_emb = (const float*)d_in[1];
        item_emb = (const float*)d_in[0];
    }
    const int*   edge_a   = (const int*)d_in[2];
    const int*   edge_b   = (const int*)d_in[3];
    const float* edge_val = (const float*)d_in[4];

    float* out = (float*)d_out;                 // F32 output
    float* out_users = out;                     // users first
    float* out_items = out + (size_t)NU * DIM;

    const long long NOUT = (long long)(NU + NI) * DIM;   // 19.2M f32

    // Workspace layout (4 B units) — flag and cnt contiguous for one memset:
    //  flag[16] | cnt[NT] | rowptr[NT+1] | cursor[NT] | bsum[256] |
    //  colS[2*NE] | valS[2*NE]
    int* flag = (int*)d_ws;
    const size_t need_units = (size_t)16 + NT + (NT + 1) + NT + 256
                            + (size_t)2 * NE + (size_t)2 * NE;
    const size_t need_bytes = need_units * 4;

    if (ws_size >= need_bytes) {
        int*   cnt    = flag + 16;
        int*   rowptr = cnt + NT;
        int*   cursor = rowptr + NT + 1;
        int*   bsum   = cursor + NT;
        int*   colS   = bsum + 256;
        float* valS   = (float*)(colS + (size_t)2 * NE);

        // flag + cnt must start at zero every launch (contiguous -> 1 memset).
        hipMemsetAsync(d_ws, 0, (size_t)(16 + NT) * 4, stream);
        edge_detect_kernel<<<512, 256, 0, stream>>>(edge_a, edge_b, NE, flag);
        finalize_kernel<<<1, 64, 0, stream>>>(flag);
        hist_kernel<<<1600, 256, 0, stream>>>(edge_a, edge_b, flag, cnt);
        scan1_kernel<<<NB, 256, 0, stream>>>(cnt, bsum);
        scan3_kernel<<<NB, 256, 0, stream>>>(cnt, bsum, rowptr, cursor);
        scatter_kernel<<<3200, 256, 0, stream>>>(edge_a, edge_b, flag, edge_val,
                                                 cursor, colS, valS);
        // Fused: user rows (gather item_emb) + item rows (gather user_emb).
        spmm_fused_kernel<<<(NT * 64 + 255) / 256, 256, 0, stream>>>(
            rowptr, colS, valS, item_emb, user_emb, out_users, out_items);
    } else {
        // Fallback: proven R8 atomic path.
        hipMemsetAsync(flag, 0, 16 * 4, stream);
        edge_detect_kernel<<<512, 256, 0, stream>>>(edge_a, edge_b, NE, flag);
        finalize_kernel<<<1, 64, 0, stream>>>(flag);
        zero_f32_kernel<<<2048, 256, 0, stream>>>(out, NOUT);
        long long nthreads = (long long)NE * 64;
        edge_atomic_kernel<<<(int)(nthreads / 256), 256, 0, stream>>>(
            edge_a, edge_b, flag, edge_val, user_emb, item_emb, out_users, out_items);
    }
}